// Round 13
// baseline (165.732 us; speedup 1.0000x reference)
//
#include <hip/hip_runtime.h>
#include <hip/hip_bf16.h>

#define NB 4
#define SEQ 2048
#define NHEADS 8
#define ROWS (NB * SEQ)

typedef __attribute__((ext_vector_type(8))) short bf16x8;
typedef __attribute__((ext_vector_type(4))) short bf16x4;
typedef __attribute__((ext_vector_type(4))) float f32x4;
typedef __attribute__((ext_vector_type(16))) float f32x16;

__device__ inline short f2bf(float x) {
    union { float f; unsigned u; } v; v.f = x;
    unsigned r = v.u + 0x7FFF + ((v.u >> 16) & 1);
    return (short)(r >> 16);
}

__device__ inline unsigned pack2bf(float a, float b) {
    __hip_bfloat162 h = __float22bfloat162_rn(make_float2(a, b));
    unsigned u; __builtin_memcpy(&u, &h, 4);
    return u;
}

// combine two packed-bf16 pairs from the two K-halves and scale: bf16 out
__device__ inline unsigned comb2(unsigned w1, unsigned w2, float inv) {
    union { unsigned v; float f; } a, b, c, d;
    a.v = w1 << 16;          b.v = w2 << 16;
    c.v = w1 & 0xffff0000u;  d.v = w2 & 0xffff0000u;
    return pack2bf((a.f + b.f) * inv, (c.f + d.f) * inv);
}

// ---------------------------------------------------------------------------
// Fused fp32 -> bf16 cast for all 5 inputs (one launch). Unit = 4 elements.
// ---------------------------------------------------------------------------
__global__ __launch_bounds__(256) void cvt_all(
    const float* __restrict__ x, const float* __restrict__ ctx,
    const float* __restrict__ wq, const float* __restrict__ wkv,
    const float* __restrict__ wo,
    short* __restrict__ xb, short* __restrict__ cb, short* __restrict__ wqb,
    short* __restrict__ wkvb, short* __restrict__ wob)
{
    const int i = blockIdx.x * 256 + threadIdx.x;
    const float* src; short* dst; int off;
    if (i < 524288)       { src = x;   dst = xb;   off = i; }
    else if (i < 1048576) { src = ctx; dst = cb;   off = i - 524288; }
    else if (i < 1081344) { src = wq;  dst = wqb;  off = i - 1048576; }
    else if (i < 1146880) { src = wkv; dst = wkvb; off = i - 1081344; }
    else                  { src = wo;  dst = wob;  off = i - 1146880; }
    const float4 v = ((const float4*)src)[off];
    uint2 o2;
    o2.x = pack2bf(v.x, v.y);
    o2.y = pack2bf(v.z, v.w);
    *(uint2*)(dst + (size_t)off * 4) = o2;
}

// ---------------------------------------------------------------------------
// Merged q+kv projection, pure bf16, 128x128 tiles, BK=64, K=256.
// XCD-local decode: row-tile ≡ flat (mod 8) -> all column-tiles of one A
// row-strip run on one XCD; A fetched from HBM once, re-reads L2-hit.
//   bid < 512  : kv tiles — rlo=bid&7, rest=bid>>3: col=rest&7, row=rlo+8*(rest>>3)
//   bid >= 512 : q tiles  — u=bid-512: rlo=u&7, rest=u>>3: col=rest&3, row=rlo+8*(rest>>2)
// launch_bounds(256,3): 3 co-resident blocks/CU overlap barrier drains.
// ---------------------------------------------------------------------------
__global__ __launch_bounds__(256, 3) void proj2(
    const short* __restrict__ xb, const short* __restrict__ wqb,
    const float* __restrict__ bq,
    const short* __restrict__ cb, const short* __restrict__ wkvb,
    const float* __restrict__ bkv,
    short* __restrict__ q2b, short* __restrict__ kv2b, float qscale)
{
    __shared__ short As[128 * 64];
    __shared__ short Ws[128 * 64];
    const int tid = threadIdx.x;
    const int bid = blockIdx.x;
    const int w = tid >> 6, lane = tid & 63, low = lane & 15, quad = lane >> 4;
    const int wm = w >> 1, wn = w & 1;
    const int K = 256;

    const short* A; const short* W; const float* bias;
    short* outp; int Ccols; float scale; int rM0, c0;
    if (bid < 512) {
        A = cb; W = wkvb; bias = bkv; outp = kv2b; Ccols = 1024; scale = 1.0f;
        const int rlo = bid & 7, rest = bid >> 3;
        c0 = (rest & 7) * 128; rM0 = (rlo + 8 * (rest >> 3)) * 128;
    } else {
        const int u = bid - 512;
        A = xb; W = wqb; bias = bq; outp = q2b; Ccols = 512; scale = qscale;
        const int rlo = u & 7, rest = u >> 3;
        c0 = (rest & 3) * 128; rM0 = (rlo + 8 * (rest >> 2)) * 128;
    }

    const int srow = tid >> 3, sj = tid & 7;

    f32x4 acc[4][4];
#pragma unroll
    for (int mt = 0; mt < 4; ++mt)
#pragma unroll
        for (int nt = 0; nt < 4; ++nt) acc[mt][nt] = (f32x4){0.f, 0.f, 0.f, 0.f};

    bf16x8 pab[4], pwb[4];
#pragma unroll
    for (int c = 0; c < 4; ++c) {
        const int row = c * 32 + srow;
        pab[c] = *(const bf16x8*)(A + (size_t)(rM0 + row) * K + sj * 8);
        pwb[c] = *(const bf16x8*)(W + (size_t)(c0 + row) * K + sj * 8);
    }

    int k0 = 0;
    for (;;) {
        __syncthreads();
#pragma unroll
        for (int c = 0; c < 4; ++c) {
            const int row = c * 32 + srow;
            const int pc = sj ^ (row & 7);
            *(bf16x8*)(&As[row * 64 + pc * 8]) = pab[c];
            *(bf16x8*)(&Ws[row * 64 + pc * 8]) = pwb[c];
        }
        __syncthreads();
        const int kn = k0 + 64;
        if (kn < K) {
#pragma unroll
            for (int c = 0; c < 4; ++c) {
                const int row = c * 32 + srow;
                pab[c] = *(const bf16x8*)(A + (size_t)(rM0 + row) * K + kn + sj * 8);
                pwb[c] = *(const bf16x8*)(W + (size_t)(c0 + row) * K + kn + sj * 8);
            }
        }
#pragma unroll
        for (int kh = 0; kh < 2; ++kh) {
            bf16x8 af[4], bfv[4];
#pragma unroll
            for (int t = 0; t < 4; ++t) {
                const int ra = wm * 64 + t * 16 + low;
                af[t] = *(const bf16x8*)(&As[ra * 64 + ((kh * 4 + quad) ^ (ra & 7)) * 8]);
                const int rb = wn * 64 + t * 16 + low;
                bfv[t] = *(const bf16x8*)(&Ws[rb * 64 + ((kh * 4 + quad) ^ (rb & 7)) * 8]);
            }
#pragma unroll
            for (int mt = 0; mt < 4; ++mt)
#pragma unroll
                for (int nt = 0; nt < 4; ++nt)
                    acc[mt][nt] = __builtin_amdgcn_mfma_f32_16x16x32_bf16(af[mt], bfv[nt], acc[mt][nt], 0, 0, 0);
        }
        k0 = kn;
        if (k0 >= K) break;
    }

#pragma unroll
    for (int nt = 0; nt < 4; ++nt) {
        const int col = c0 + wn * 64 + nt * 16 + low;
        const float bv = bias[col];
#pragma unroll
        for (int mt = 0; mt < 4; ++mt) {
            const size_t rbase = (size_t)(rM0 + wm * 64 + mt * 16 + quad * 4);
#pragma unroll
            for (int r = 0; r < 4; ++r)
                outp[(rbase + r) * Ccols + col] = f2bf((acc[mt][nt][r] + bv) * scale);
        }
    }
}

// ---------------------------------------------------------------------------
// Split-K combine: ob[r][e] = (num1[r][e]+num2[r][e]) / (l1[r][h]+l2[r][h]).
// Memory-bound, 8 elems/thread, 2048 blocks.
// ---------------------------------------------------------------------------
__global__ __launch_bounds__(256) void combine(
    const short* __restrict__ num, const float* __restrict__ lbuf,
    short* __restrict__ ob)
{
    const size_t NHALF = (size_t)ROWS * 512;
    const int R8 = ROWS * 8;
    const int i = blockIdx.x * 256 + threadIdx.x;   // unit = 8 elems
    const size_t e0 = (size_t)i * 8;
    const int row = (int)(e0 >> 9);
    const int h = (int)((e0 >> 6) & 7);
    const float inv = 1.f / (lbuf[row * 8 + h] + lbuf[R8 + row * 8 + h]);
    const uint4 a = *(const uint4*)(num + e0);
    const uint4 b = *(const uint4*)(num + NHALF + e0);
    uint4 o;
    o.x = comb2(a.x, b.x, inv);
    o.y = comb2(a.y, b.y, inv);
    o.z = comb2(a.z, b.z, inv);
    o.w = comb2(a.w, b.w, inv);
    *(uint4*)(ob + e0) = o;
}

// ---------------------------------------------------------------------------
// Plain bf16 o-GEMM: out = ob * Wo^T + bo, 128x128 tiles, fp32 out.
// Grid dim3(2, 64) = 128 blocks; A read 2x (32 MB), W L2-resident.
// ---------------------------------------------------------------------------
__global__ __launch_bounds__(256, 3) void gemm128_o(
    const short* __restrict__ A, const short* __restrict__ W,
    const float* __restrict__ bias, float* __restrict__ out)
{
    const int K = 512, Ccols = 256;
    __shared__ short As[128 * 64];
    __shared__ short Ws[128 * 64];
    const int tid = threadIdx.x;
    const int w = tid >> 6, lane = tid & 63, low = lane & 15, quad = lane >> 4;
    const int wm = w >> 1, wn = w & 1;
    const int rM0 = blockIdx.y * 128, c0 = blockIdx.x * 128;
    const int srow = tid >> 3, sj = tid & 7;

    f32x4 acc[4][4];
#pragma unroll
    for (int mt = 0; mt < 4; ++mt)
#pragma unroll
        for (int nt = 0; nt < 4; ++nt) acc[mt][nt] = (f32x4){0.f, 0.f, 0.f, 0.f};

    bf16x8 pab[4], pwb[4];
#pragma unroll
    for (int c = 0; c < 4; ++c) {
        const int row = c * 32 + srow;
        pab[c] = *(const bf16x8*)(A + (size_t)(rM0 + row) * K + sj * 8);
        pwb[c] = *(const bf16x8*)(W + (size_t)(c0 + row) * K + sj * 8);
    }

    int k0 = 0;
    for (;;) {
        __syncthreads();
#pragma unroll
        for (int c = 0; c < 4; ++c) {
            const int row = c * 32 + srow;
            const int pc = sj ^ (row & 7);
            *(bf16x8*)(&As[row * 64 + pc * 8]) = pab[c];
            *(bf16x8*)(&Ws[row * 64 + pc * 8]) = pwb[c];
        }
        __syncthreads();
        const int kn = k0 + 64;
        if (kn < K) {
#pragma unroll
            for (int c = 0; c < 4; ++c) {
                const int row = c * 32 + srow;
                pab[c] = *(const bf16x8*)(A + (size_t)(rM0 + row) * K + kn + sj * 8);
                pwb[c] = *(const bf16x8*)(W + (size_t)(c0 + row) * K + kn + sj * 8);
            }
        }
#pragma unroll
        for (int kh = 0; kh < 2; ++kh) {
            bf16x8 af[4], bfv[4];
#pragma unroll
            for (int t = 0; t < 4; ++t) {
                const int ra = wm * 64 + t * 16 + low;
                af[t] = *(const bf16x8*)(&As[ra * 64 + ((kh * 4 + quad) ^ (ra & 7)) * 8]);
                const int rb = wn * 64 + t * 16 + low;
                bfv[t] = *(const bf16x8*)(&Ws[rb * 64 + ((kh * 4 + quad) ^ (rb & 7)) * 8]);
            }
#pragma unroll
            for (int mt = 0; mt < 4; ++mt)
#pragma unroll
                for (int nt = 0; nt < 4; ++nt)
                    acc[mt][nt] = __builtin_amdgcn_mfma_f32_16x16x32_bf16(af[mt], bfv[nt], acc[mt][nt], 0, 0, 0);
        }
        k0 = kn;
        if (k0 >= K) break;
    }

#pragma unroll
    for (int nt = 0; nt < 4; ++nt) {
        const int col = c0 + wn * 64 + nt * 16 + low;
        const float bv = bias[col];
#pragma unroll
        for (int mt = 0; mt < 4; ++mt) {
            const size_t rbase = (size_t)(rM0 + wm * 64 + mt * 16 + quad * 4);
#pragma unroll
            for (int r = 0; r < 4; ++r)
                out[(rbase + r) * Ccols + col] = acc[mt][nt][r] + bv;
        }
    }
}

// ---------------------------------------------------------------------------
// MFMA flash attention (32x32x16), R9/R12 structure (unchanged): split-K x2
// over keys, XCD-swizzled 1-D grid, reads pre-projected/pre-scaled q2.
// Layouts (32x32x16, verified m74/m101):
//   A: A[m = lane&31][k = (lane>>5)*8 + j]
//   B: B[k = (lane>>5)*8 + j][n = lane&31]
//   C: col(n) = lane&31, row(m) = (reg&3) + 8*(reg>>2) + 4*(lane>>5)
// ---------------------------------------------------------------------------
#define KST 72
#define VST 72
#define PST 72

__global__ __launch_bounds__(256) void attn_mfma(
    const short* __restrict__ q2,   // ROWS x 512 bf16 (pre-scaled)
    const short* __restrict__ kv2,  // ROWS x 1024 bf16
    short* __restrict__ numb,       // 2 x ROWS x 512 bf16 (unnormalized O)
    float* __restrict__ lbuf)       // 2 x ROWS x 8 fp32
{
    __shared__ short Ks[64 * KST];
    __shared__ short Vt[64 * VST];
    __shared__ short Ps[4][32 * PST];

    const int tid = threadIdx.x;
    const int w = tid >> 6;
    const int lane = tid & 63;
    const int l31 = lane & 31;
    const int h2 = lane >> 5;

    // XCD swizzle decode
    const int flat = blockIdx.x;
    const int h = flat & 7;
    const int rest = flat >> 3;
    const int half = rest & 1;
    const int rest2 = rest >> 1;
    const int qtile = rest2 & 15;
    const int b = rest2 >> 4;
    const int iq0 = qtile * 128;
    const int jt0 = half * 16;

    // --- Q fragments: B operand, 4 k-steps, registers all kernel ---
    bf16x8 qr[4];
#pragma unroll
    for (int st = 0; st < 4; ++st)
        qr[st] = *(const bf16x8*)(q2 + (size_t)(b * SEQ + iq0 + w * 32 + l31) * 512
                                  + h * 64 + st * 16 + h2 * 8);

    const short* kbase = kv2 + (size_t)(b * SEQ) * 1024 + h * 64;
    const short* vbase = kbase + 512;
    short* pw = &Ps[w][0];

    float lsum = 0.f;                 // partial: query = l31, this lane's keys
    f32x16 oacc[2];                   // [dg]; col = dim, rows = queries
#pragma unroll
    for (int dg = 0; dg < 2; ++dg)
#pragma unroll
        for (int r = 0; r < 16; ++r) oacc[dg][r] = 0.f;

    // staging indices
    const int krow = tid >> 2;          // key row 0..63
    const int kc = (tid & 3) * 16;      // dim chunk (shorts)
    const int vk4 = (tid & 15) * 4;     // key base (V^T)
    const int vd4 = (tid >> 4) * 4;     // dim base 0..60

    // --- prefetch first tile of this half ---
    bf16x8 pk0, pk1;
    bf16x4 pv0, pv1, pv2, pv3;
    {
        const short* ksrc = kbase + (size_t)(jt0 * 64 + krow) * 1024 + kc;
        pk0 = *(const bf16x8*)(ksrc);
        pk1 = *(const bf16x8*)(ksrc + 8);
        const short* vs = vbase + (size_t)(jt0 * 64 + vk4) * 1024 + vd4;
        pv0 = *(const bf16x4*)(vs);
        pv1 = *(const bf16x4*)(vs + 1024);
        pv2 = *(const bf16x4*)(vs + 2048);
        pv3 = *(const bf16x4*)(vs + 3072);
    }

    for (int jt = jt0; jt < jt0 + 16; ++jt) {
        __syncthreads();
        *(bf16x8*)(&Ks[krow * KST + kc]) = pk0;
        *(bf16x8*)(&Ks[krow * KST + kc + 8]) = pk1;
        {
            bf16x4 c0_, c1_, c2_, c3_;
            c0_[0] = pv0[0]; c0_[1] = pv1[0]; c0_[2] = pv2[0]; c0_[3] = pv3[0];
            c1_[0] = pv0[1]; c1_[1] = pv1[1]; c1_[2] = pv2[1]; c1_[3] = pv3[1];
            c2_[0] = pv0[2]; c2_[1] = pv1[2]; c2_[2] = pv2[2]; c2_[3] = pv3[2];
            c3_[0] = pv0[3]; c3_[1] = pv1[3]; c3_[2] = pv2[3]; c3_[3] = pv3[3];
            *(bf16x4*)(&Vt[(vd4 + 0) * VST + vk4]) = c0_;
            *(bf16x4*)(&Vt[(vd4 + 1) * VST + vk4]) = c1_;
            *(bf16x4*)(&Vt[(vd4 + 2) * VST + vk4]) = c2_;
            *(bf16x4*)(&Vt[(vd4 + 3) * VST + vk4]) = c3_;
        }
        __syncthreads();

        // prefetch next tile
        if (jt + 1 < jt0 + 16) {
            const short* ksrc = kbase + (size_t)((jt + 1) * 64 + krow) * 1024 + kc;
            pk0 = *(const bf16x8*)(ksrc);
            pk1 = *(const bf16x8*)(ksrc + 8);
            const short* vs = vbase + (size_t)((jt + 1) * 64 + vk4) * 1024 + vd4;
            pv0 = *(const bf16x4*)(vs);
            pv1 = *(const bf16x4*)(vs + 1024);
            pv2 = *(const bf16x4*)(vs + 2048);
            pv3 = *(const bf16x4*)(vs + 3072);
        }

        // --- S^T = K Q^T (2 key-groups x 4 k-steps), P = exp2, b64 stores ---
#pragma unroll
        for (int kg = 0; kg < 2; ++kg) {
            f32x16 s;
#pragma unroll
            for (int r = 0; r < 16; ++r) s[r] = 0.f;
#pragma unroll
            for (int st = 0; st < 4; ++st) {
                const bf16x8 kf = *(const bf16x8*)(&Ks[(kg * 32 + l31) * KST + st * 16 + h2 * 8]);
                s = __builtin_amdgcn_mfma_f32_32x32x16_bf16(kf, qr[st], s, 0, 0, 0);
            }
#pragma unroll
            for (int g = 0; g < 4; ++g) {
                const float p0 = __builtin_amdgcn_exp2f(s[4 * g + 0]);
                const float p1 = __builtin_amdgcn_exp2f(s[4 * g + 1]);
                const float p2 = __builtin_amdgcn_exp2f(s[4 * g + 2]);
                const float p3 = __builtin_amdgcn_exp2f(s[4 * g + 3]);
                lsum += (p0 + p1) + (p2 + p3);
                uint2 u;
                u.x = pack2bf(p0, p1);
                u.y = pack2bf(p2, p3);
                *(uint2*)(&pw[l31 * PST + kg * 32 + 8 * g + 4 * h2]) = u;
            }
        }
        __builtin_amdgcn_wave_barrier();

        // --- O += P V (4 k-steps x 2 dim-groups) ---
#pragma unroll
        for (int st = 0; st < 4; ++st) {
            const bf16x8 pf = *(const bf16x8*)(&pw[l31 * PST + st * 16 + h2 * 8]);
#pragma unroll
            for (int dg = 0; dg < 2; ++dg) {
                const bf16x8 vf = *(const bf16x8*)(&Vt[(dg * 32 + l31) * VST + st * 16 + h2 * 8]);
                oacc[dg] = __builtin_amdgcn_mfma_f32_32x32x16_bf16(pf, vf, oacc[dg], 0, 0, 0);
            }
        }
        __builtin_amdgcn_wave_barrier();
    }

    // --- epilogue: combine h2 halves of lsum; store partial l and O ---
    lsum += __shfl_xor(lsum, 32);     // all 64 keys for query = w*32 + l31
    short* nb = numb + (size_t)half * ROWS * 512;
    float* lb = lbuf + (size_t)half * ROWS * 8;
    if (lane < 32)
        lb[(size_t)(b * SEQ + iq0 + w * 32 + l31) * 8 + h] = lsum;
#pragma unroll
    for (int dg = 0; dg < 2; ++dg)
#pragma unroll
        for (int r = 0; r < 16; ++r) {
            const int qrow = w * 32 + (r & 3) + 8 * (r >> 2) + 4 * h2;
            nb[(size_t)(b * SEQ + iq0 + qrow) * 512 + h * 64 + dg * 32 + l31] =
                f2bf(oacc[dg][r]);
        }
}

// ---------------------------------------------------------------------------
extern "C" void kernel_launch(void* const* d_in, const int* in_sizes, int n_in,
                              void* d_out, int out_size, void* d_ws, size_t ws_size,
                              hipStream_t stream) {
    const float* x   = (const float*)d_in[0];  // (4,2048,256)
    const float* ctx = (const float*)d_in[1];  // (4,2048,256)
    const float* Wq  = (const float*)d_in[2];  // (512,256)
    const float* bq  = (const float*)d_in[3];
    const float* Wkv = (const float*)d_in[4];  // (1024,256)
    const float* bkv = (const float*)d_in[5];
    const float* Wo  = (const float*)d_in[6];  // (256,512)
    const float* bo  = (const float*)d_in[7];
    float* out = (float*)d_out;                // (4,2048,256) fp32

    short* xb   = (short*)d_ws;                         // ROWS*256
    short* cb   = xb + (size_t)ROWS * 256;              // ROWS*256
    short* wqb  = cb + (size_t)ROWS * 256;              // 131072
    short* wkvb = wqb + 131072;                         // 262144
    short* wob  = wkvb + 262144;                        // 131072
    short* q2b  = wob + 131072;                         // ROWS*512
    short* kv2b = q2b + (size_t)ROWS * 512;             // ROWS*1024
    short* numb = kv2b + (size_t)ROWS * 1024;           // 2*ROWS*512
    float* lbuf = (float*)(numb + (size_t)2 * ROWS * 512); // 2*ROWS*8
    short* ob   = xb;   // alias: xb+cb (ROWS*512 shorts) dead after proj2

    const float qscale = 0.125f * 1.44269504088896f;   // softmax scale + log2e

    cvt_all<<<4608, 256, 0, stream>>>(x, ctx, Wq, Wkv, Wo,
                                      xb, cb, wqb, wkvb, wob);
    // merged q+kv projection, 128x128 tiles, XCD-local A strips (768 blocks)
    proj2<<<768, 256, 0, stream>>>(xb, wqb, bq, cb, wkvb, bkv,
                                   q2b, kv2b, qscale);
    // attention, split-K x2, 32x32x16 MFMA, XCD-swizzled 1-D grid (1024 blocks)
    attn_mfma<<<NB * NHEADS * (SEQ / 128) * 2, 256, 0, stream>>>(
        q2b, kv2b, numb, lbuf);
    // split-K combine (memory-bound), writes normalized bf16 O over xb/cb
    combine<<<ROWS * 512 / 8 / 256, 256, 0, stream>>>(numb, lbuf, ob);
    // out = ob * Wo^T + bo (plain bf16 GEMM, 128x128 tiles)
    gemm128_o<<<dim3(2, 64), 256, 0, stream>>>(ob, wob, bo, out);
}